// Round 2
// baseline (5760.066 us; speedup 1.0000x reference)
//
#include <hip/hip_runtime.h>

#define BB 2
#define TTL 2048
#define DM 1024
#define DI 2048
#define DSN 16
#define DTR 64
#define MM (BB*TTL)   // 4096

static __device__ __forceinline__ float softplus_f(float x){
  return (x > 20.f) ? x : __logf(1.f + __expf(x));
}
static __device__ __forceinline__ float sigmoid_f(float x){ return 1.f/(1.f+__expf(-x)); }

struct GemmP {
  const float* A; const float* A2; int lda; int splitK; // A row-major MxK; if A2, cols >= splitK come from A2
  const float* B; int ldb;        // B row-major K x N
  int N, K;                       // M is always 4096
  const float* bias;              // nullable, length N
  float* out0; int ldo0;
  float* out1;                    // EPI 3 second half
  const float* x; const float* u; const float* alpha;  // EPI 2 extras
  int splitN;
};

// 64x64 tile, 256 threads, 4x4 per thread, fp32.
// EPI: 0=store f32, 1=bias+softplus, 2=gate epilogue (x_gated),
//      3=split store xi/z, 5=bias+store
template<int EPI>
__global__ __launch_bounds__(256) void gemm_k(GemmP p){
  __shared__ __align__(16) float As[16][64];
  __shared__ __align__(16) float Bs[16][64];
  const int tid = threadIdx.x;
  const int tx = tid & 15, ty = tid >> 4;
  const int m0 = blockIdx.x * 64, n0 = blockIdx.y * 64;
  const int ar = tid >> 2, ak = (tid & 3) * 4;   // A stage: 4 consecutive k
  const int bk = tid >> 4, bn = (tid & 15) * 4;  // B stage: 4 consecutive n
  float acc[4][4] = {};

  for (int k0 = 0; k0 < p.K; k0 += 16){
    int kk = k0 + ak;
    const float* Ap = p.A;
    int col = kk;
    if (p.A2 && kk >= p.splitK){ Ap = p.A2; col = kk - p.splitK; }
    long ab = (long)(m0 + ar) * p.lda + col;
    As[ak+0][ar]=Ap[ab]; As[ak+1][ar]=Ap[ab+1]; As[ak+2][ar]=Ap[ab+2]; As[ak+3][ar]=Ap[ab+3];
    long bb = (long)(k0 + bk) * p.ldb + n0 + bn;
    #pragma unroll
    for (int i=0;i<4;i++){
      int n = n0 + bn + i;
      Bs[bk][bn+i] = (n < p.N) ? p.B[bb + i] : 0.f;
    }
    __syncthreads();
    #pragma unroll
    for (int kq=0;kq<16;kq++){
      float4 av = *(const float4*)&As[kq][ty*4];
      float4 bv = *(const float4*)&Bs[kq][tx*4];
      acc[0][0] += av.x*bv.x; acc[0][1] += av.x*bv.y; acc[0][2] += av.x*bv.z; acc[0][3] += av.x*bv.w;
      acc[1][0] += av.y*bv.x; acc[1][1] += av.y*bv.y; acc[1][2] += av.y*bv.z; acc[1][3] += av.y*bv.w;
      acc[2][0] += av.z*bv.x; acc[2][1] += av.z*bv.y; acc[2][2] += av.z*bv.z; acc[2][3] += av.z*bv.w;
      acc[3][0] += av.w*bv.x; acc[3][1] += av.w*bv.y; acc[3][2] += av.w*bv.z; acc[3][3] += av.w*bv.w;
    }
    __syncthreads();
  }

  float alpha_v = 0.f;
  if (EPI == 2) alpha_v = *p.alpha;
  #pragma unroll
  for (int i=0;i<4;i++){
    int m = m0 + ty*4 + i;
    #pragma unroll
    for (int j=0;j<4;j++){
      int n = n0 + tx*4 + j;
      if (n >= p.N) continue;
      float v = acc[i][j];
      if (p.bias) v += p.bias[n];
      if (EPI == 0){
        p.out0[(long)m*p.ldo0 + n] = v;
      } else if (EPI == 1){
        p.out0[(long)m*p.ldo0 + n] = softplus_f(v);
      } else if (EPI == 2){
        float d   = softplus_f(v);
        float did = d * __expf(-alpha_v * p.u[m]);
        float g   = did / (1.f + did);
        p.out0[(long)m*p.ldo0 + n] = p.x[(long)m*p.ldo0 + n] * g;
      } else if (EPI == 3){
        if (n < p.splitN) p.out0[(long)m*p.splitN + n] = v;
        else              p.out1[(long)m*p.splitN + (n - p.splitN)] = v;
      } else if (EPI == 5){
        p.out0[(long)m*p.ldo0 + n] = v;
      }
    }
  }
}

// causal depthwise conv (dir=0: window t-3..t; dir=1: window t..t+3 reversed) + silu
__global__ __launch_bounds__(256) void conv_silu_k(const float* __restrict__ xi,
    const float* __restrict__ w, const float* __restrict__ cb,
    float* __restrict__ xc, int dir){
  long idx = (long)blockIdx.x*256 + threadIdx.x;   // over MM*DI
  int c = (int)(idx & (DI-1));
  int m = (int)(idx >> 11);
  int b = m >> 11;
  int t = m & (TTL-1);
  float acc = cb[c];
  #pragma unroll
  for (int k=0;k<4;k++){
    int tt = dir ? (t + 3 - k) : (t - 3 + k);
    if (tt >= 0 && tt < TTL)
      acc += w[c*4 + k] * xi[(long)(b*TTL + tt)*DI + c];
  }
  xc[idx] = acc * sigmoid_f(acc);
}

// selective scan: one lane per (b, c, s); 16-lane shuffle reduce over s.
// y[m,c] = (sum_s h*C + xc*Dp) * silu(z)
__global__ __launch_bounds__(256) void scan_k(const float* __restrict__ dt,
    const float* __restrict__ xdb, const float* __restrict__ xc,
    const float* __restrict__ z, const float* __restrict__ A_log,
    const float* __restrict__ Dp, float* __restrict__ y, int dir){
  int g = blockIdx.x*256 + threadIdx.x;
  int s = g & 15;
  int c = (g >> 4) & (DI-1);
  int b = g >> 15;
  float A   = -__expf(A_log[c*DSN + s]);
  float Dpc = Dp[c];
  float h = 0.f;

  int t0 = dir ? (TTL-1) : 0;
  long m = (long)b*TTL + t0;
  float dtv = dt [m*DI + c];
  float xv  = xc [m*DI + c];
  float Bv  = xdb[m*96 + DTR + s];
  float Cv  = xdb[m*96 + DTR + DSN + s];

  #pragma unroll 1
  for (int i=0;i<TTL;i++){
    float dtv2=0.f, xv2=0.f, Bv2=0.f, Cv2=0.f; long m2 = m;
    if (i+1 < TTL){
      int t2 = dir ? (TTL-2-i) : (i+1);
      m2 = (long)b*TTL + t2;
      dtv2 = dt [m2*DI + c];
      xv2  = xc [m2*DI + c];
      Bv2  = xdb[m2*96 + DTR + s];
      Cv2  = xdb[m2*96 + DTR + DSN + s];
    }
    h = __expf(dtv*A)*h + dtv*Bv*xv;
    float ps = h*Cv;
    ps += __shfl_xor(ps, 1);
    ps += __shfl_xor(ps, 2);
    ps += __shfl_xor(ps, 4);
    ps += __shfl_xor(ps, 8);
    if (s == 0){
      float zv = z[m*DI + c];
      y[m*DI + c] = (ps + xv*Dpc) * (zv * sigmoid_f(zv));
    }
    dtv=dtv2; xv=xv2; Bv=Bv2; Cv=Cv2; m=m2;
  }
}

extern "C" void kernel_launch(void* const* d_in, const int* in_sizes, int n_in,
                              void* d_out, int out_size, void* d_ws, size_t ws_size,
                              hipStream_t stream) {
  const float* x       = (const float*)d_in[0];
  const float* u       = (const float*)d_in[1];
  const float* alphap  = (const float*)d_in[2];
  const float* W_delta = (const float*)d_in[3];
  const float* b_delta = (const float*)d_in[4];
  const float* W_proj  = (const float*)d_in[5];
  const float* b_proj  = (const float*)d_in[6];

  // fp32 workspace layout: 38,141,952 floats = 145.5 MiB
  float* ws      = (float*)d_ws;
  float* x_gated = ws;                 // 4096*1024
  float* xi      = ws + 4194304;       // 4096*2048  (reused as y after scan)
  float* zb      = ws + 12582912;      // 4096*2048
  float* xc      = ws + 20971520;      // 4096*2048
  float* dtb     = ws + 29360128;      // 4096*2048
  float* xdb     = ws + 37748736;      // 4096*96

  float* o_main = (float*)d_out;           // Output 0: out
  float* o_fwd  = o_main + 4194304;        // Output 1: fwd_out
  float* o_bwd  = o_main + 2*4194304;      // Output 2: bwd_out

  // ---- G1: delta_raw GEMM + gating epilogue -> x_gated (fp32) ----
  {
    GemmP p{};
    p.A = x; p.lda = DM; p.B = W_delta; p.ldb = DM; p.N = DM; p.K = DM;
    p.bias = b_delta; p.out0 = x_gated; p.ldo0 = DM;
    p.x = x; p.u = u; p.alpha = alphap;
    gemm_k<2><<<dim3(MM/64, DM/64), 256, 0, stream>>>(p);
  }

  for (int dir = 0; dir < 2; dir++){
    const int base = 7 + 9*dir;
    const float* W_in   = (const float*)d_in[base+0];
    const float* conv_w = (const float*)d_in[base+1];
    const float* conv_b = (const float*)d_in[base+2];
    const float* W_x    = (const float*)d_in[base+3];
    const float* W_dt   = (const float*)d_in[base+4];
    const float* b_dt   = (const float*)d_in[base+5];
    const float* A_log  = (const float*)d_in[base+6];
    const float* Dp     = (const float*)d_in[base+7];
    const float* W_out  = (const float*)d_in[base+8];

    // G2: xz = x_gated @ W_in, split into xi / z
    {
      GemmP p{};
      p.A = x_gated; p.lda = DM; p.B = W_in; p.ldb = 2*DI; p.N = 2*DI; p.K = DM;
      p.out0 = xi; p.out1 = zb; p.splitN = DI;
      gemm_k<3><<<dim3(MM/64, (2*DI)/64), 256, 0, stream>>>(p);
    }
    // conv + silu -> xc
    conv_silu_k<<<(MM*DI)/256, 256, 0, stream>>>(xi, conv_w, conv_b, xc, dir);
    // G3: xdb = xc @ W_x  (N=96)
    {
      GemmP p{};
      p.A = xc; p.lda = DI; p.B = W_x; p.ldb = 96; p.N = 96; p.K = DI;
      p.out0 = xdb; p.ldo0 = 96;
      gemm_k<0><<<dim3(MM/64, 2), 256, 0, stream>>>(p);
    }
    // G4: dt = softplus(dt_lo @ W_dt + b_dt)   (A = xdb cols 0..63, lda=96)
    {
      GemmP p{};
      p.A = xdb; p.lda = 96; p.B = W_dt; p.ldb = DI; p.N = DI; p.K = DTR;
      p.bias = b_dt; p.out0 = dtb; p.ldo0 = DI;
      gemm_k<1><<<dim3(MM/64, DI/64), 256, 0, stream>>>(p);
    }
    // selective scan (+ D skip + z gate) -> y (into xi buffer)
    scan_k<<<(BB*DI*DSN)/256, 256, 0, stream>>>(dtb, xdb, xc, zb, A_log, Dp, xi, dir);
    // G7: dir_out = y @ W_out  -> fp32 output slot (also consumed by G8)
    {
      GemmP p{};
      p.A = xi; p.lda = DI; p.B = W_out; p.ldb = DM; p.N = DM; p.K = DI;
      p.out0 = dir ? o_bwd : o_fwd; p.ldo0 = DM;
      gemm_k<0><<<dim3(MM/64, DM/64), 256, 0, stream>>>(p);
    }
  }

  // G8: out = cat @ W_proj + b_proj (A split: cols 0..1023 from fwd, 1024.. from bwd)
  {
    GemmP p{};
    p.A = o_fwd; p.A2 = o_bwd; p.lda = DM; p.splitK = DM;
    p.B = W_proj; p.ldb = DM; p.N = DM; p.K = 2*DM;
    p.bias = b_proj; p.out0 = o_main; p.ldo0 = DM;
    gemm_k<5><<<dim3(MM/64, DM/64), 256, 0, stream>>>(p);
  }
}

// Round 3
// 3169.665 us; speedup vs baseline: 1.8172x; 1.8172x over previous
//
#include <hip/hip_runtime.h>

#define BB 2
#define TTL 2048
#define DM 1024
#define DI 2048
#define DSN 16
#define DTR 64
#define MM (BB*TTL)   // 4096
#define NC 16
#define CL (TTL/NC)   // 128

static __device__ __forceinline__ float softplus_f(float x){
  return (x > 20.f) ? x : __logf(1.f + __expf(x));
}
static __device__ __forceinline__ float sigmoid_f(float x){ return 1.f/(1.f+__expf(-x)); }

struct GemmP {
  const float* A; const float* A2; int lda; int splitK; // A row-major MxK; if A2, cols >= splitK come from A2
  const float* B; int ldb;        // B row-major K x N
  int N, K;                       // M is always 4096
  const float* bias;              // nullable, length N
  float* out0; int ldo0;
  float* out1;                    // EPI 3 second half
  const float* x; const float* u; const float* alpha;  // EPI 2 extras
  int splitN;
};

// 64x64 tile, 256 threads, 4x4 per thread, fp32.
// EPI: 0=store f32, 1=bias+softplus, 2=gate epilogue (x_gated),
//      3=split store xi/z, 5=bias+store
template<int EPI>
__global__ __launch_bounds__(256) void gemm_k(GemmP p){
  __shared__ __align__(16) float As[16][64];
  __shared__ __align__(16) float Bs[16][64];
  const int tid = threadIdx.x;
  const int tx = tid & 15, ty = tid >> 4;
  const int m0 = blockIdx.x * 64, n0 = blockIdx.y * 64;
  const int ar = tid >> 2, ak = (tid & 3) * 4;   // A stage: 4 consecutive k
  const int bk = tid >> 4, bn = (tid & 15) * 4;  // B stage: 4 consecutive n
  float acc[4][4] = {};

  for (int k0 = 0; k0 < p.K; k0 += 16){
    int kk = k0 + ak;
    const float* Ap = p.A;
    int col = kk;
    if (p.A2 && kk >= p.splitK){ Ap = p.A2; col = kk - p.splitK; }
    long ab = (long)(m0 + ar) * p.lda + col;
    As[ak+0][ar]=Ap[ab]; As[ak+1][ar]=Ap[ab+1]; As[ak+2][ar]=Ap[ab+2]; As[ak+3][ar]=Ap[ab+3];
    long bb = (long)(k0 + bk) * p.ldb + n0 + bn;
    #pragma unroll
    for (int i=0;i<4;i++){
      int n = n0 + bn + i;
      Bs[bk][bn+i] = (n < p.N) ? p.B[bb + i] : 0.f;
    }
    __syncthreads();
    #pragma unroll
    for (int kq=0;kq<16;kq++){
      float4 av = *(const float4*)&As[kq][ty*4];
      float4 bv = *(const float4*)&Bs[kq][tx*4];
      acc[0][0] += av.x*bv.x; acc[0][1] += av.x*bv.y; acc[0][2] += av.x*bv.z; acc[0][3] += av.x*bv.w;
      acc[1][0] += av.y*bv.x; acc[1][1] += av.y*bv.y; acc[1][2] += av.y*bv.z; acc[1][3] += av.y*bv.w;
      acc[2][0] += av.z*bv.x; acc[2][1] += av.z*bv.y; acc[2][2] += av.z*bv.z; acc[2][3] += av.z*bv.w;
      acc[3][0] += av.w*bv.x; acc[3][1] += av.w*bv.y; acc[3][2] += av.w*bv.z; acc[3][3] += av.w*bv.w;
    }
    __syncthreads();
  }

  float alpha_v = 0.f;
  if (EPI == 2) alpha_v = *p.alpha;
  #pragma unroll
  for (int i=0;i<4;i++){
    int m = m0 + ty*4 + i;
    #pragma unroll
    for (int j=0;j<4;j++){
      int n = n0 + tx*4 + j;
      if (n >= p.N) continue;
      float v = acc[i][j];
      if (p.bias) v += p.bias[n];
      if (EPI == 0){
        p.out0[(long)m*p.ldo0 + n] = v;
      } else if (EPI == 1){
        p.out0[(long)m*p.ldo0 + n] = softplus_f(v);
      } else if (EPI == 2){
        float d   = softplus_f(v);
        float did = d * __expf(-alpha_v * p.u[m]);
        float g   = did / (1.f + did);
        p.out0[(long)m*p.ldo0 + n] = p.x[(long)m*p.ldo0 + n] * g;
      } else if (EPI == 3){
        if (n < p.splitN) p.out0[(long)m*p.splitN + n] = v;
        else              p.out1[(long)m*p.splitN + (n - p.splitN)] = v;
      } else if (EPI == 5){
        p.out0[(long)m*p.ldo0 + n] = v;
      }
    }
  }
}

// causal depthwise conv (dir=0: window t-3..t; dir=1: window t..t+3 reversed) + silu
__global__ __launch_bounds__(256) void conv_silu_k(const float* __restrict__ xi,
    const float* __restrict__ w, const float* __restrict__ cb,
    float* __restrict__ xc, int dir){
  long idx = (long)blockIdx.x*256 + threadIdx.x;   // over MM*DI
  int c = (int)(idx & (DI-1));
  int m = (int)(idx >> 11);
  int b = m >> 11;
  int t = m & (TTL-1);
  float acc = cb[c];
  #pragma unroll
  for (int k=0;k<4;k++){
    int tt = dir ? (t + 3 - k) : (t - 3 + k);
    if (tt >= 0 && tt < TTL)
      acc += w[c*4 + k] * xi[(long)(b*TTL + tt)*DI + c];
  }
  xc[idx] = acc * sigmoid_f(acc);
}

// ---- chunk-parallel linear scan ----
// thread id bits: s(4) | c(11) | k(4) | b(1); chunk k covers logical steps
// j in [k*CL, (k+1)*CL); t = dir ? TTL-1-j : j.

// Phase 1: local scan with h0=0; store final h and cumulative product P.
__global__ __launch_bounds__(256) void scan_p1(const float* __restrict__ dt,
    const float* __restrict__ xdb, const float* __restrict__ xc,
    const float* __restrict__ A_log, float* __restrict__ hpart,
    float* __restrict__ Ppart, int dir){
  int g = blockIdx.x*256 + threadIdx.x;
  int s = g & 15;
  int c = (g >> 4) & (DI-1);
  int k = (g >> 15) & (NC-1);
  int b = g >> 19;
  float A = -__expf(A_log[c*DSN + s]);
  float h = 0.f, P = 1.f;
  int jb = k*CL;
  #pragma unroll 4
  for (int i=0;i<CL;i++){
    int j = jb + i;
    int t = dir ? (TTL-1-j) : j;
    long m = (long)b*TTL + t;
    float dtv = dt [m*DI + c];
    float xv  = xc [m*DI + c];
    float Bv  = xdb[m*96 + DTR + s];
    float a = __expf(dtv*A);
    P *= a;
    h = a*h + dtv*Bv*xv;
  }
  long o = (((long)b*NC + k)*DI + c)*DSN + s;
  hpart[o] = h; Ppart[o] = P;
}

// Phase 2: sequential combine over chunks; overwrite hpart[k] with chunk-start h0.
__global__ __launch_bounds__(256) void scan_p2(float* __restrict__ hpart,
    const float* __restrict__ Ppart){
  int g = blockIdx.x*256 + threadIdx.x;   // over BB*DI*DSN
  int s = g & 15;
  int c = (g >> 4) & (DI-1);
  int b = g >> 15;
  float run = 0.f;
  #pragma unroll
  for (int k=0;k<NC;k++){
    long o = (((long)b*NC + k)*DI + c)*DSN + s;
    float hk = hpart[o];
    float Pk = Ppart[o];
    hpart[o] = run;
    run = Pk*run + hk;
  }
}

// Phase 3: re-scan from true h0, compute y = (sum_s h*C + xc*Dp) * silu(z).
__global__ __launch_bounds__(256) void scan_p3(const float* __restrict__ dt,
    const float* __restrict__ xdb, const float* __restrict__ xc,
    const float* __restrict__ z, const float* __restrict__ A_log,
    const float* __restrict__ Dp, const float* __restrict__ hpart,
    float* __restrict__ y, int dir){
  int g = blockIdx.x*256 + threadIdx.x;
  int s = g & 15;
  int c = (g >> 4) & (DI-1);
  int k = (g >> 15) & (NC-1);
  int b = g >> 19;
  float A   = -__expf(A_log[c*DSN + s]);
  float Dpc = Dp[c];
  float h = hpart[(((long)b*NC + k)*DI + c)*DSN + s];
  int jb = k*CL;
  #pragma unroll 2
  for (int i=0;i<CL;i++){
    int j = jb + i;
    int t = dir ? (TTL-1-j) : j;
    long m = (long)b*TTL + t;
    float dtv = dt [m*DI + c];
    float xv  = xc [m*DI + c];
    float Bv  = xdb[m*96 + DTR + s];
    float Cv  = xdb[m*96 + DTR + DSN + s];
    h = __expf(dtv*A)*h + dtv*Bv*xv;
    float ps = h*Cv;
    ps += __shfl_xor(ps, 1);
    ps += __shfl_xor(ps, 2);
    ps += __shfl_xor(ps, 4);
    ps += __shfl_xor(ps, 8);
    if (s == 0){
      float zv = z[m*DI + c];
      y[m*DI + c] = (ps + xv*Dpc) * (zv * sigmoid_f(zv));
    }
  }
}

// fallback: fully sequential scan (round-2 version) if ws too small
__global__ __launch_bounds__(256) void scan_k(const float* __restrict__ dt,
    const float* __restrict__ xdb, const float* __restrict__ xc,
    const float* __restrict__ z, const float* __restrict__ A_log,
    const float* __restrict__ Dp, float* __restrict__ y, int dir){
  int g = blockIdx.x*256 + threadIdx.x;
  int s = g & 15;
  int c = (g >> 4) & (DI-1);
  int b = g >> 15;
  float A   = -__expf(A_log[c*DSN + s]);
  float Dpc = Dp[c];
  float h = 0.f;
  int t0 = dir ? (TTL-1) : 0;
  long m = (long)b*TTL + t0;
  float dtv = dt [m*DI + c];
  float xv  = xc [m*DI + c];
  float Bv  = xdb[m*96 + DTR + s];
  float Cv  = xdb[m*96 + DTR + DSN + s];
  #pragma unroll 1
  for (int i=0;i<TTL;i++){
    float dtv2=0.f, xv2=0.f, Bv2=0.f, Cv2=0.f; long m2 = m;
    if (i+1 < TTL){
      int t2 = dir ? (TTL-2-i) : (i+1);
      m2 = (long)b*TTL + t2;
      dtv2 = dt [m2*DI + c];
      xv2  = xc [m2*DI + c];
      Bv2  = xdb[m2*96 + DTR + s];
      Cv2  = xdb[m2*96 + DTR + DSN + s];
    }
    h = __expf(dtv*A)*h + dtv*Bv*xv;
    float ps = h*Cv;
    ps += __shfl_xor(ps, 1);
    ps += __shfl_xor(ps, 2);
    ps += __shfl_xor(ps, 4);
    ps += __shfl_xor(ps, 8);
    if (s == 0){
      float zv = z[m*DI + c];
      y[m*DI + c] = (ps + xv*Dpc) * (zv * sigmoid_f(zv));
    }
    dtv=dtv2; xv=xv2; Bv=Bv2; Cv=Cv2; m=m2;
  }
}

extern "C" void kernel_launch(void* const* d_in, const int* in_sizes, int n_in,
                              void* d_out, int out_size, void* d_ws, size_t ws_size,
                              hipStream_t stream) {
  const float* x       = (const float*)d_in[0];
  const float* u       = (const float*)d_in[1];
  const float* alphap  = (const float*)d_in[2];
  const float* W_delta = (const float*)d_in[3];
  const float* b_delta = (const float*)d_in[4];
  const float* W_proj  = (const float*)d_in[5];
  const float* b_proj  = (const float*)d_in[6];

  // fp32 workspace layout
  float* ws      = (float*)d_ws;
  float* x_gated = ws;                 // 4096*1024
  float* xi      = ws + 4194304;       // 4096*2048  (reused as y after scan)
  float* zb      = ws + 12582912;      // 4096*2048
  float* xc      = ws + 20971520;      // 4096*2048
  float* dtb     = ws + 29360128;      // 4096*2048
  float* xdb     = ws + 37748736;      // 4096*96
  float* hpart   = ws + 38141952;      // 2*16*2048*16 = 1,048,576
  float* Ppart   = ws + 39190528;      // 1,048,576
  const size_t ws_need = (size_t)40239104 * 4;   // 153.5 MiB
  const bool chunked = (ws_size >= ws_need);

  float* o_main = (float*)d_out;           // Output 0: out
  float* o_fwd  = o_main + 4194304;        // Output 1: fwd_out
  float* o_bwd  = o_main + 2*4194304;      // Output 2: bwd_out

  // ---- G1: delta_raw GEMM + gating epilogue -> x_gated (fp32) ----
  {
    GemmP p{};
    p.A = x; p.lda = DM; p.B = W_delta; p.ldb = DM; p.N = DM; p.K = DM;
    p.bias = b_delta; p.out0 = x_gated; p.ldo0 = DM;
    p.x = x; p.u = u; p.alpha = alphap;
    gemm_k<2><<<dim3(MM/64, DM/64), 256, 0, stream>>>(p);
  }

  for (int dir = 0; dir < 2; dir++){
    const int base = 7 + 9*dir;
    const float* W_in   = (const float*)d_in[base+0];
    const float* conv_w = (const float*)d_in[base+1];
    const float* conv_b = (const float*)d_in[base+2];
    const float* W_x    = (const float*)d_in[base+3];
    const float* W_dt   = (const float*)d_in[base+4];
    const float* b_dt   = (const float*)d_in[base+5];
    const float* A_log  = (const float*)d_in[base+6];
    const float* Dp     = (const float*)d_in[base+7];
    const float* W_out  = (const float*)d_in[base+8];

    // G2: xz = x_gated @ W_in, split into xi / z
    {
      GemmP p{};
      p.A = x_gated; p.lda = DM; p.B = W_in; p.ldb = 2*DI; p.N = 2*DI; p.K = DM;
      p.out0 = xi; p.out1 = zb; p.splitN = DI;
      gemm_k<3><<<dim3(MM/64, (2*DI)/64), 256, 0, stream>>>(p);
    }
    // conv + silu -> xc
    conv_silu_k<<<(MM*DI)/256, 256, 0, stream>>>(xi, conv_w, conv_b, xc, dir);
    // G3: xdb = xc @ W_x  (N=96)
    {
      GemmP p{};
      p.A = xc; p.lda = DI; p.B = W_x; p.ldb = 96; p.N = 96; p.K = DI;
      p.out0 = xdb; p.ldo0 = 96;
      gemm_k<0><<<dim3(MM/64, 2), 256, 0, stream>>>(p);
    }
    // G4: dt = softplus(dt_lo @ W_dt + b_dt)   (A = xdb cols 0..63, lda=96)
    {
      GemmP p{};
      p.A = xdb; p.lda = 96; p.B = W_dt; p.ldb = DI; p.N = DI; p.K = DTR;
      p.bias = b_dt; p.out0 = dtb; p.ldo0 = DI;
      gemm_k<1><<<dim3(MM/64, DI/64), 256, 0, stream>>>(p);
    }
    // selective scan (+ D skip + z gate) -> y (into xi buffer)
    if (chunked){
      scan_p1<<<(BB*NC*DI*DSN)/256, 256, 0, stream>>>(dtb, xdb, xc, A_log, hpart, Ppart, dir);
      scan_p2<<<(BB*DI*DSN)/256, 256, 0, stream>>>(hpart, Ppart);
      scan_p3<<<(BB*NC*DI*DSN)/256, 256, 0, stream>>>(dtb, xdb, xc, zb, A_log, Dp, hpart, xi, dir);
    } else {
      scan_k<<<(BB*DI*DSN)/256, 256, 0, stream>>>(dtb, xdb, xc, zb, A_log, Dp, xi, dir);
    }
    // G7: dir_out = y @ W_out  -> fp32 output slot (also consumed by G8)
    {
      GemmP p{};
      p.A = xi; p.lda = DI; p.B = W_out; p.ldb = DM; p.N = DM; p.K = DI;
      p.out0 = dir ? o_bwd : o_fwd; p.ldo0 = DM;
      gemm_k<0><<<dim3(MM/64, DM/64), 256, 0, stream>>>(p);
    }
  }

  // G8: out = cat @ W_proj + b_proj (A split: cols 0..1023 from fwd, 1024.. from bwd)
  {
    GemmP p{};
    p.A = o_fwd; p.A2 = o_bwd; p.lda = DM; p.splitK = DM;
    p.B = W_proj; p.ldb = DM; p.N = DM; p.K = 2*DM;
    p.bias = b_proj; p.out0 = o_main; p.ldo0 = DM;
    gemm_k<5><<<dim3(MM/64, DM/64), 256, 0, stream>>>(p);
  }
}

// Round 4
// 1310.783 us; speedup vs baseline: 4.3944x; 2.4181x over previous
//
#include <hip/hip_runtime.h>
#include <hip/hip_bf16.h>

#define BB 2
#define TTL 2048
#define DM 1024
#define DI 2048
#define DSN 16
#define DTR 64
#define MM (BB*TTL)   // 4096
#define NC 16
#define CL (TTL/NC)   // 128

typedef __hip_bfloat16 hbf;
typedef short short8 __attribute__((ext_vector_type(8)));
typedef float floatx4 __attribute__((ext_vector_type(4)));

static __device__ __forceinline__ float softplus_f(float x){
  return (x > 20.f) ? x : __logf(1.f + __expf(x));
}
static __device__ __forceinline__ float sigmoid_f(float x){ return 1.f/(1.f+__expf(-x)); }
static __device__ __forceinline__ float b2f(hbf v){ return __bfloat162float(v); }
static __device__ __forceinline__ hbf  f2b(float v){ return __float2bfloat16(v); }

#define ASYNC_CP(g, l) __builtin_amdgcn_global_load_lds( \
    (const __attribute__((address_space(1))) void*)(g), \
    (__attribute__((address_space(3))) void*)(l), 16, 0, 0)

struct MGemmP {
  const hbf* A; int lda;      // bf16 row-major M x K
  const hbf* Bt; int ldb;     // bf16 N x K (pre-transposed), rows padded to >= gridN*128
  int N, K;
  const float* bias;          // nullable
  float* out0; int ldo0;
  hbf*  ob0;  int ldob0; int col0;
  const float* x; const float* u; const float* alpha;   // EPI 0 extras
};

// 128x128 tile, BK=32, 4 waves (2x2), 4x4 x mfma_f32_16x16x32_bf16 per wave.
// EPI: 0=gate->bf16, 1=split xi_bf/z_f32, 2=xdb f32 + dtlo bf16,
//      3=softplus f32, 4=f32 + bf16(cat col0), 5=bias f32
template<int EPI>
__global__ __launch_bounds__(256) void mgemm_k(MGemmP p){
  __shared__ short As[128*32];
  __shared__ short Bs[128*32];
  const int tid  = threadIdx.x;
  const int lane = tid & 63;
  const int wave = tid >> 6;
  const int wr = wave & 1, wc = wave >> 1;
  const int m0 = blockIdx.x*128, n0 = blockIdx.y*128;
  const int q = lane >> 4, rr = lane & 15;

  floatx4 acc[4][4];
  #pragma unroll
  for (int i=0;i<4;i++)
    #pragma unroll
    for (int j=0;j<4;j++) acc[i][j] = (floatx4){0.f,0.f,0.f,0.f};

  const int c0 = tid, c1 = tid + 256;   // 16B chunks: row=c>>2, col8=(c&3)*8

  for (int k0 = 0; k0 < p.K; k0 += 32){
    ASYNC_CP(p.A  + (long)(m0 + (c0>>2))*p.lda + k0 + (c0&3)*8, As + c0*8);
    ASYNC_CP(p.A  + (long)(m0 + (c1>>2))*p.lda + k0 + (c1&3)*8, As + c1*8);
    ASYNC_CP(p.Bt + (long)(n0 + (c0>>2))*p.ldb + k0 + (c0&3)*8, Bs + c0*8);
    ASYNC_CP(p.Bt + (long)(n0 + (c1>>2))*p.ldb + k0 + (c1&3)*8, Bs + c1*8);
    __syncthreads();
    short8 af[4], bfr[4];
    #pragma unroll
    for (int i=0;i<4;i++){
      af[i]  = *(const short8*)(As + (wr*64 + i*16 + rr)*32 + q*8);
      bfr[i] = *(const short8*)(Bs + (wc*64 + i*16 + rr)*32 + q*8);
    }
    #pragma unroll
    for (int i=0;i<4;i++)
      #pragma unroll
      for (int j=0;j<4;j++)
        acc[i][j] = __builtin_amdgcn_mfma_f32_16x16x32_bf16(af[i], bfr[j], acc[i][j], 0, 0, 0);
    __syncthreads();
  }

  float alpha_v = 0.f;
  if (EPI == 0) alpha_v = *p.alpha;
  #pragma unroll
  for (int mi=0; mi<4; mi++){
    #pragma unroll
    for (int r=0; r<4; r++){
      const int m = m0 + wr*64 + mi*16 + q*4 + r;
      #pragma unroll
      for (int ni=0; ni<4; ni++){
        const int n = n0 + wc*64 + ni*16 + rr;
        if (n >= p.N) continue;
        float v = acc[mi][ni][r];
        if (p.bias) v += p.bias[n];
        if (EPI == 0){
          float d   = softplus_f(v);
          float did = d * __expf(-alpha_v * p.u[m]);
          float g   = did / (1.f + did);
          p.ob0[(long)m*p.ldob0 + n] = f2b(p.x[(long)m*p.ldob0 + n] * g);
        } else if (EPI == 1){
          if (n < DI) p.ob0[(long)m*DI + n] = f2b(v);
          else        p.out0[(long)m*DI + (n - DI)] = v;
        } else if (EPI == 2){
          p.out0[(long)m*96 + n] = v;
          if (n < DTR) p.ob0[(long)m*DTR + n] = f2b(v);
        } else if (EPI == 3){
          p.out0[(long)m*p.ldo0 + n] = softplus_f(v);
        } else if (EPI == 4){
          p.out0[(long)m*p.ldo0 + n] = v;
          p.ob0[(long)m*p.ldob0 + p.col0 + n] = f2b(v);
        } else if (EPI == 5){
          p.out0[(long)m*p.ldo0 + n] = v;
        }
      }
    }
  }
}

// transpose + fp32->bf16: W[K][N] -> Wt[Npad][K], rows >= N zero-filled
__global__ __launch_bounds__(256) void trans_bf(const float* __restrict__ W,
    hbf* __restrict__ Wt, int K, int N){
  __shared__ float t[32][33];
  const int k0 = blockIdx.x*32, n0 = blockIdx.y*32;
  const int lx = threadIdx.x & 31, ly = threadIdx.x >> 5;  // 32 x 8
  #pragma unroll
  for (int i=0;i<32;i+=8){
    int n = n0 + lx;
    t[ly+i][lx] = (n < N) ? W[(long)(k0+ly+i)*N + n] : 0.f;
  }
  __syncthreads();
  #pragma unroll
  for (int i=0;i<32;i+=8)
    Wt[(long)(n0+ly+i)*K + k0 + lx] = f2b(t[lx][ly+i]);
}

// fp32 -> bf16 elementwise (n multiple of 1024)
__global__ __launch_bounds__(256) void cvt_bf(const float* __restrict__ a,
    hbf* __restrict__ o){
  long i = ((long)blockIdx.x*256 + threadIdx.x) * 4;
  float4 v = *(const float4*)(a + i);
  o[i+0] = f2b(v.x); o[i+1] = f2b(v.y); o[i+2] = f2b(v.z); o[i+3] = f2b(v.w);
}

// causal depthwise conv + silu; reads bf16 xi, writes bf16 xc
__global__ __launch_bounds__(256) void conv_silu_k(const hbf* __restrict__ xi,
    const float* __restrict__ w, const float* __restrict__ cb,
    hbf* __restrict__ xc, int dir){
  long idx = (long)blockIdx.x*256 + threadIdx.x;   // over MM*DI
  int c = (int)(idx & (DI-1));
  int m = (int)(idx >> 11);
  int b = m >> 11;
  int t = m & (TTL-1);
  float acc = cb[c];
  #pragma unroll
  for (int k=0;k<4;k++){
    int tt = dir ? (t + 3 - k) : (t - 3 + k);
    if (tt >= 0 && tt < TTL)
      acc += w[c*4 + k] * b2f(xi[(long)(b*TTL + tt)*DI + c]);
  }
  xc[idx] = f2b(acc * sigmoid_f(acc));
}

// ---- chunk-parallel scan (3 phases) ----
__global__ __launch_bounds__(256) void scan_p1(const float* __restrict__ dt,
    const float* __restrict__ xdb, const hbf* __restrict__ xc,
    const float* __restrict__ A_log, float* __restrict__ hpart,
    float* __restrict__ Ppart, int dir){
  int g = blockIdx.x*256 + threadIdx.x;
  int s = g & 15;
  int c = (g >> 4) & (DI-1);
  int k = (g >> 15) & (NC-1);
  int b = g >> 19;
  float A = -__expf(A_log[c*DSN + s]);
  float h = 0.f, P = 1.f;
  int jb = k*CL;
  #pragma unroll 4
  for (int i=0;i<CL;i++){
    int j = jb + i;
    int t = dir ? (TTL-1-j) : j;
    long m = (long)b*TTL + t;
    float dtv = dt [m*DI + c];
    float xv  = b2f(xc[m*DI + c]);
    float Bv  = xdb[m*96 + DTR + s];
    float a = __expf(dtv*A);
    P *= a;
    h = a*h + dtv*Bv*xv;
  }
  long o = (((long)b*NC + k)*DI + c)*DSN + s;
  hpart[o] = h; Ppart[o] = P;
}

__global__ __launch_bounds__(256) void scan_p2(float* __restrict__ hpart,
    const float* __restrict__ Ppart){
  int g = blockIdx.x*256 + threadIdx.x;   // BB*DI*DSN
  int s = g & 15;
  int c = (g >> 4) & (DI-1);
  int b = g >> 15;
  float run = 0.f;
  #pragma unroll
  for (int k=0;k<NC;k++){
    long o = (((long)b*NC + k)*DI + c)*DSN + s;
    float hk = hpart[o];
    float Pk = Ppart[o];
    hpart[o] = run;
    run = Pk*run + hk;
  }
}

__global__ __launch_bounds__(256) void scan_p3(const float* __restrict__ dt,
    const float* __restrict__ xdb, const hbf* __restrict__ xc,
    const float* __restrict__ z, const float* __restrict__ A_log,
    const float* __restrict__ Dp, const float* __restrict__ hpart,
    hbf* __restrict__ y, int dir){
  int g = blockIdx.x*256 + threadIdx.x;
  int s = g & 15;
  int c = (g >> 4) & (DI-1);
  int k = (g >> 15) & (NC-1);
  int b = g >> 19;
  float A   = -__expf(A_log[c*DSN + s]);
  float Dpc = Dp[c];
  float h = hpart[(((long)b*NC + k)*DI + c)*DSN + s];
  int jb = k*CL;
  #pragma unroll 2
  for (int i=0;i<CL;i++){
    int j = jb + i;
    int t = dir ? (TTL-1-j) : j;
    long m = (long)b*TTL + t;
    float dtv = dt [m*DI + c];
    float xv  = b2f(xc[m*DI + c]);
    float Bv  = xdb[m*96 + DTR + s];
    float Cv  = xdb[m*96 + DTR + DSN + s];
    h = __expf(dtv*A)*h + dtv*Bv*xv;
    float ps = h*Cv;
    ps += __shfl_xor(ps, 1);
    ps += __shfl_xor(ps, 2);
    ps += __shfl_xor(ps, 4);
    ps += __shfl_xor(ps, 8);
    if (s == 0){
      float zv = z[m*DI + c];
      y[m*DI + c] = f2b((ps + xv*Dpc) * (zv * sigmoid_f(zv)));
    }
  }
}

extern "C" void kernel_launch(void* const* d_in, const int* in_sizes, int n_in,
                              void* d_out, int out_size, void* d_ws, size_t ws_size,
                              hipStream_t stream) {
  const float* x       = (const float*)d_in[0];
  const float* u       = (const float*)d_in[1];
  const float* alphap  = (const float*)d_in[2];
  const float* W_delta = (const float*)d_in[3];
  const float* b_delta = (const float*)d_in[4];
  const float* W_proj  = (const float*)d_in[5];
  const float* b_proj  = (const float*)d_in[6];

  // workspace layout (byte offsets), total 155,975,680 B = 148.8 MB
  char* W = (char*)d_ws;
  float* zb     = (float*)(W + 0);            // 4096*2048 f32
  float* dtb    = (float*)(W + 33554432);     // 4096*2048 f32
  float* xdb    = (float*)(W + 67108864);     // 4096*96  f32
  float* hpart  = (float*)(W + 68681728);     // 1M f32
  float* Ppart  = (float*)(W + 72876032);     // 1M f32
  hbf* xi_y_bf  = (hbf*)(W + 77070336);       // 8M bf16 (xi then y, per dir)
  hbf* xc_bf    = (hbf*)(W + 93847552);       // 8M bf16
  hbf* xg_bf    = (hbf*)(W + 110624768);      // 4M bf16 (x_gated)
  hbf* cat_bf   = (hbf*)(W + 119013376);      // 8M bf16
  hbf* xw_bf    = (hbf*)(W + 135790592);      // 4M bf16 (x_bf, then Wt_in per dir)
  hbf* Wt_delta = (hbf*)(W + 144179200);      // 1024*1024
  hbf* Wt_proj  = (hbf*)(W + 146276352);      // 1024*2048
  hbf* Wt_out   = (hbf*)(W + 150470656);      // 1024*2048
  hbf* Wt_x     = (hbf*)(W + 154664960);      // 128*2048 (pad from 96)
  hbf* Wt_dt    = (hbf*)(W + 155189248);      // 2048*64
  hbf* dtlo_bf  = (hbf*)(W + 155451392);      // 4096*64

  float* o_main = (float*)d_out;
  float* o_fwd  = o_main + 4194304;
  float* o_bwd  = o_main + 2*4194304;

  // upfront converts
  cvt_bf<<<MM*DM/1024, 256, 0, stream>>>(x, xw_bf);
  trans_bf<<<dim3(DM/32, DM/32), 256, 0, stream>>>(W_delta, Wt_delta, DM, DM);
  trans_bf<<<dim3(2*DM/32, DM/32), 256, 0, stream>>>(W_proj, Wt_proj, 2*DM, DM);

  // G1: x @ W_delta + gate epilogue -> x_gated (bf16)
  {
    MGemmP p{};
    p.A = xw_bf; p.lda = DM; p.Bt = Wt_delta; p.ldb = DM; p.N = DM; p.K = DM;
    p.bias = b_delta; p.ob0 = xg_bf; p.ldob0 = DM;
    p.x = x; p.u = u; p.alpha = alphap;
    mgemm_k<0><<<dim3(MM/128, DM/128), 256, 0, stream>>>(p);
  }

  for (int dir = 0; dir < 2; dir++){
    const int base = 7 + 9*dir;
    const float* W_in   = (const float*)d_in[base+0];
    const float* conv_w = (const float*)d_in[base+1];
    const float* conv_b = (const float*)d_in[base+2];
    const float* W_x    = (const float*)d_in[base+3];
    const float* W_dt   = (const float*)d_in[base+4];
    const float* b_dt   = (const float*)d_in[base+5];
    const float* A_log  = (const float*)d_in[base+6];
    const float* Dp     = (const float*)d_in[base+7];
    const float* W_out  = (const float*)d_in[base+8];

    // per-dir weight transposes (xw_bf region free after G1 / prior dir)
    trans_bf<<<dim3(DM/32, 4096/32), 256, 0, stream>>>(W_in, xw_bf, DM, 2*DI);
    trans_bf<<<dim3(DI/32, 128/32), 256, 0, stream>>>(W_x, Wt_x, DI, 96);
    trans_bf<<<dim3(DTR/32, DI/32), 256, 0, stream>>>(W_dt, Wt_dt, DTR, DI);
    trans_bf<<<dim3(DI/32, DM/32), 256, 0, stream>>>(W_out, Wt_out, DI, DM);

    // G2: xz = x_gated @ W_in -> xi (bf16) | z (fp32)
    {
      MGemmP p{};
      p.A = xg_bf; p.lda = DM; p.Bt = xw_bf; p.ldb = DM; p.N = 2*DI; p.K = DM;
      p.ob0 = xi_y_bf; p.out0 = zb;
      mgemm_k<1><<<dim3(MM/128, (2*DI)/128), 256, 0, stream>>>(p);
    }
    conv_silu_k<<<(MM*DI)/256, 256, 0, stream>>>(xi_y_bf, conv_w, conv_b, xc_bf, dir);
    // G3: xdb = xc @ W_x (N=96, padded B) -> xdb f32 + dtlo bf16
    {
      MGemmP p{};
      p.A = xc_bf; p.lda = DI; p.Bt = Wt_x; p.ldb = DI; p.N = 96; p.K = DI;
      p.out0 = xdb; p.ob0 = dtlo_bf;
      mgemm_k<2><<<dim3(MM/128, 1), 256, 0, stream>>>(p);
    }
    // G4: dt = softplus(dt_lo @ W_dt + b_dt) -> f32
    {
      MGemmP p{};
      p.A = dtlo_bf; p.lda = DTR; p.Bt = Wt_dt; p.ldb = DTR; p.N = DI; p.K = DTR;
      p.bias = b_dt; p.out0 = dtb; p.ldo0 = DI;
      mgemm_k<3><<<dim3(MM/128, DI/128), 256, 0, stream>>>(p);
    }
    // scan
    scan_p1<<<(BB*NC*DI*DSN)/256, 256, 0, stream>>>(dtb, xdb, xc_bf, A_log, hpart, Ppart, dir);
    scan_p2<<<(BB*DI*DSN)/256, 256, 0, stream>>>(hpart, Ppart);
    scan_p3<<<(BB*NC*DI*DSN)/256, 256, 0, stream>>>(dtb, xdb, xc_bf, zb, A_log, Dp, hpart, xi_y_bf, dir);
    // G7: dir_out = y @ W_out -> fp32 output + bf16 cat
    {
      MGemmP p{};
      p.A = xi_y_bf; p.lda = DI; p.Bt = Wt_out; p.ldb = DI; p.N = DM; p.K = DI;
      p.out0 = dir ? o_bwd : o_fwd; p.ldo0 = DM;
      p.ob0 = cat_bf; p.ldob0 = 2*DM; p.col0 = dir*DM;
      mgemm_k<4><<<dim3(MM/128, DM/128), 256, 0, stream>>>(p);
    }
  }

  // G8: out = cat @ W_proj + b_proj -> fp32
  {
    MGemmP p{};
    p.A = cat_bf; p.lda = 2*DM; p.Bt = Wt_proj; p.ldb = 2*DM; p.N = DM; p.K = 2*DM;
    p.bias = b_proj; p.out0 = o_main; p.ldo0 = DM;
    mgemm_k<5><<<dim3(MM/128, DM/128), 256, 0, stream>>>(p);
  }
}

// Round 5
// 927.697 us; speedup vs baseline: 6.2090x; 1.4129x over previous
//
#include <hip/hip_runtime.h>
#include <hip/hip_bf16.h>

#define BB 2
#define TTL 2048
#define DM 1024
#define DI 2048
#define DSN 16
#define DTR 64
#define MM (BB*TTL)   // 4096
#define NC 32
#define CL (TTL/NC)   // 64

typedef __hip_bfloat16 hbf;
typedef short short8 __attribute__((ext_vector_type(8)));
typedef float floatx4 __attribute__((ext_vector_type(4)));

static __device__ __forceinline__ float softplus_f(float x){
  return (x > 20.f) ? x : __logf(1.f + __expf(x));
}
static __device__ __forceinline__ float sigmoid_f(float x){ return 1.f/(1.f+__expf(-x)); }
static __device__ __forceinline__ float b2f(hbf v){ return __bfloat162float(v); }
static __device__ __forceinline__ hbf  f2b(float v){ return __float2bfloat16(v); }

#define ASYNC_CP(g, l) __builtin_amdgcn_global_load_lds( \
    (const __attribute__((address_space(1))) void*)(g), \
    (__attribute__((address_space(3))) void*)(l), 16, 0, 0)

struct MGemmP {
  const hbf* A; int lda;      // bf16 row-major M x K
  const hbf* Bt; int ldb;     // bf16 N x K (pre-transposed), rows padded to >= gridN*128
  int N, K;
  const float* bias;          // nullable
  float* out0; int ldo0;
  hbf*  ob0;  int ldob0; int col0;
  hbf*  ob1;
  const float* x; const float* u; const float* alpha;   // EPI 0 extras
};

// 128x128 tile, BK=32, 4 waves (2x2), 4x4 x mfma_f32_16x16x32_bf16 per wave.
// EPI: 0=gate->bf16, 1=split xi_bf/z_bf, 2=dtlo bf16 + bcpk f32,
//      3=softplus f32, 4=f32 + bf16(cat col0), 5=bias f32
template<int EPI>
__global__ __launch_bounds__(256) void mgemm_k(MGemmP p){
  __shared__ short As[128*32];
  __shared__ short Bs[128*32];
  const int tid  = threadIdx.x;
  const int lane = tid & 63;
  const int wave = tid >> 6;
  const int wr = wave & 1, wc = wave >> 1;
  const int m0 = blockIdx.x*128, n0 = blockIdx.y*128;
  const int q = lane >> 4, rr = lane & 15;

  floatx4 acc[4][4];
  #pragma unroll
  for (int i=0;i<4;i++)
    #pragma unroll
    for (int j=0;j<4;j++) acc[i][j] = (floatx4){0.f,0.f,0.f,0.f};

  const int c0 = tid, c1 = tid + 256;   // 16B chunks: row=c>>2, col8=(c&3)*8

  for (int k0 = 0; k0 < p.K; k0 += 32){
    ASYNC_CP(p.A  + (long)(m0 + (c0>>2))*p.lda + k0 + (c0&3)*8, As + c0*8);
    ASYNC_CP(p.A  + (long)(m0 + (c1>>2))*p.lda + k0 + (c1&3)*8, As + c1*8);
    ASYNC_CP(p.Bt + (long)(n0 + (c0>>2))*p.ldb + k0 + (c0&3)*8, Bs + c0*8);
    ASYNC_CP(p.Bt + (long)(n0 + (c1>>2))*p.ldb + k0 + (c1&3)*8, Bs + c1*8);
    __syncthreads();
    short8 af[4], bfr[4];
    #pragma unroll
    for (int i=0;i<4;i++){
      af[i]  = *(const short8*)(As + (wr*64 + i*16 + rr)*32 + q*8);
      bfr[i] = *(const short8*)(Bs + (wc*64 + i*16 + rr)*32 + q*8);
    }
    #pragma unroll
    for (int i=0;i<4;i++)
      #pragma unroll
      for (int j=0;j<4;j++)
        acc[i][j] = __builtin_amdgcn_mfma_f32_16x16x32_bf16(af[i], bfr[j], acc[i][j], 0, 0, 0);
    __syncthreads();
  }

  float alpha_v = 0.f;
  if (EPI == 0) alpha_v = *p.alpha;
  #pragma unroll
  for (int mi=0; mi<4; mi++){
    #pragma unroll
    for (int r=0; r<4; r++){
      const int m = m0 + wr*64 + mi*16 + q*4 + r;
      #pragma unroll
      for (int ni=0; ni<4; ni++){
        const int n = n0 + wc*64 + ni*16 + rr;
        if (n >= p.N) continue;
        float v = acc[mi][ni][r];
        if (p.bias) v += p.bias[n];
        if (EPI == 0){
          float d   = softplus_f(v);
          float did = d * __expf(-alpha_v * p.u[m]);
          float g   = did / (1.f + did);
          p.ob0[(long)m*p.ldob0 + n] = f2b(p.x[(long)m*p.ldob0 + n] * g);
        } else if (EPI == 1){
          if (n < DI) p.ob0[(long)m*DI + n] = f2b(v);
          else        p.ob1[(long)m*DI + (n - DI)] = f2b(v);
        } else if (EPI == 2){
          if (n < DTR) p.ob0[(long)m*DTR + n] = f2b(v);
          else         p.out0[(long)m*32 + (n - DTR)] = v;
        } else if (EPI == 3){
          p.out0[(long)m*p.ldo0 + n] = softplus_f(v);
        } else if (EPI == 4){
          p.out0[(long)m*p.ldo0 + n] = v;
          p.ob0[(long)m*p.ldob0 + p.col0 + n] = f2b(v);
        } else if (EPI == 5){
          p.out0[(long)m*p.ldo0 + n] = v;
        }
      }
    }
  }
}

// transpose + fp32->bf16: W[K][N] -> Wt[Npad][K], rows >= N zero-filled
__global__ __launch_bounds__(256) void trans_bf(const float* __restrict__ W,
    hbf* __restrict__ Wt, int K, int N){
  __shared__ float t[32][33];
  const int k0 = blockIdx.x*32, n0 = blockIdx.y*32;
  const int lx = threadIdx.x & 31, ly = threadIdx.x >> 5;  // 32 x 8
  #pragma unroll
  for (int i=0;i<32;i+=8){
    int n = n0 + lx;
    t[ly+i][lx] = (n < N) ? W[(long)(k0+ly+i)*N + n] : 0.f;
  }
  __syncthreads();
  #pragma unroll
  for (int i=0;i<32;i+=8)
    Wt[(long)(n0+ly+i)*K + k0 + lx] = f2b(t[lx][ly+i]);
}

// fp32 -> bf16 elementwise (n multiple of 1024)
__global__ __launch_bounds__(256) void cvt_bf(const float* __restrict__ a,
    hbf* __restrict__ o){
  long i = ((long)blockIdx.x*256 + threadIdx.x) * 4;
  float4 v = *(const float4*)(a + i);
  o[i+0] = f2b(v.x); o[i+1] = f2b(v.y); o[i+2] = f2b(v.z); o[i+3] = f2b(v.w);
}

// causal depthwise conv + silu; reads bf16 xi, writes bf16 xc
__global__ __launch_bounds__(256) void conv_silu_k(const hbf* __restrict__ xi,
    const float* __restrict__ w, const float* __restrict__ cb,
    hbf* __restrict__ xc, int dir){
  long idx = (long)blockIdx.x*256 + threadIdx.x;   // over MM*DI
  int c = (int)(idx & (DI-1));
  int m = (int)(idx >> 11);
  int b = m >> 11;
  int t = m & (TTL-1);
  float acc = cb[c];
  #pragma unroll
  for (int k=0;k<4;k++){
    int tt = dir ? (t + 3 - k) : (t - 3 + k);
    if (tt >= 0 && tt < TTL)
      acc += w[c*4 + k] * b2f(xi[(long)(b*TTL + tt)*DI + c]);
  }
  xc[idx] = f2b(acc * sigmoid_f(acc));
}

// ---- chunk-parallel scan, s-in-registers layout ----
// thread = (b, chunk k, channel c); 16 h states in VGPRs; B/C staged in LDS.
// hpart layout: [b,k][s][c]  (coalesced across lanes for every s)

__global__ __launch_bounds__(256) void scan_p1(const float* __restrict__ dt,
    const float* __restrict__ bcpk, const hbf* __restrict__ xc,
    const float* __restrict__ A_log, float* __restrict__ hpart,
    float* __restrict__ Ppart, int dir){
  __shared__ float bc[CL*32];
  const int tid = threadIdx.x;
  const int cblk = blockIdx.x & 7;
  const int k = (blockIdx.x >> 3) & (NC-1);
  const int b = blockIdx.x >> 8;
  const int c = cblk*256 + tid;
  const int tlo = dir ? (TTL - (k+1)*CL) : k*CL;
  {
    const float4* src = (const float4*)(bcpk + ((long)b*TTL + tlo)*32);
    float4* dst = (float4*)bc;
    #pragma unroll
    for (int i=0;i<(CL*8)/256;i++) dst[tid + i*256] = src[tid + i*256];
  }
  __syncthreads();

  float Aa[16];
  #pragma unroll
  for (int qg=0;qg<4;qg++){
    float4 t4 = *(const float4*)(A_log + (long)c*DSN + qg*4);
    Aa[qg*4+0] = -__expf(t4.x); Aa[qg*4+1] = -__expf(t4.y);
    Aa[qg*4+2] = -__expf(t4.z); Aa[qg*4+3] = -__expf(t4.w);
  }
  float h[16], P[16];
  #pragma unroll
  for (int s=0;s<16;s++){ h[s]=0.f; P[s]=1.f; }

  const int tstart = dir ? (TTL-1 - k*CL) : k*CL;
  const long step = dir ? -(long)DI : (long)DI;
  const float* dtp = dt + ((long)b*TTL + tstart)*DI + c;
  const hbf*   xcp = xc + ((long)b*TTL + tstart)*DI + c;
  float dtv = *dtp, xv = b2f(*xcp);

  #pragma unroll 1
  for (int i=0;i<CL;i++){
    float dtn = dtv, xn = xv;
    if (i+1 < CL){ dtp += step; xcp += step; dtn = *dtp; xn = b2f(*xcp); }
    const int r = dir ? (CL-1-i) : i;
    const float* bcr = bc + r*32;
    const float t1 = dtv*xv;
    #pragma unroll
    for (int sg=0;sg<4;sg++){
      float4 Bv = *(const float4*)(bcr + sg*4);
      float a0 = __expf(dtv*Aa[sg*4+0]); P[sg*4+0]*=a0; h[sg*4+0]=a0*h[sg*4+0]+t1*Bv.x;
      float a1 = __expf(dtv*Aa[sg*4+1]); P[sg*4+1]*=a1; h[sg*4+1]=a1*h[sg*4+1]+t1*Bv.y;
      float a2 = __expf(dtv*Aa[sg*4+2]); P[sg*4+2]*=a2; h[sg*4+2]=a2*h[sg*4+2]+t1*Bv.z;
      float a3 = __expf(dtv*Aa[sg*4+3]); P[sg*4+3]*=a3; h[sg*4+3]=a3*h[sg*4+3]+t1*Bv.w;
    }
    dtv = dtn; xv = xn;
  }
  long o = ((long)(b*NC + k)*DSN)*DI + c;
  #pragma unroll
  for (int s=0;s<16;s++){ hpart[o + (long)s*DI] = h[s]; Ppart[o + (long)s*DI] = P[s]; }
}

__global__ __launch_bounds__(256) void scan_p2(float* __restrict__ hpart,
    const float* __restrict__ Ppart){
  int g = blockIdx.x*256 + threadIdx.x;   // BB*DI*DSN
  int c = g & (DI-1);
  int s = (g >> 11) & 15;
  int b = g >> 15;
  float run = 0.f;
  #pragma unroll
  for (int k=0;k<NC;k++){
    long o = ((long)(b*NC + k)*DSN + s)*DI + c;
    float hk = hpart[o];
    float Pk = Ppart[o];
    hpart[o] = run;
    run = Pk*run + hk;
  }
}

__global__ __launch_bounds__(256) void scan_p3(const float* __restrict__ dt,
    const float* __restrict__ bcpk, const hbf* __restrict__ xc,
    const hbf* __restrict__ z, const float* __restrict__ A_log,
    const float* __restrict__ Dp, const float* __restrict__ hpart,
    hbf* __restrict__ y, int dir){
  __shared__ float bc[CL*32];
  const int tid = threadIdx.x;
  const int cblk = blockIdx.x & 7;
  const int k = (blockIdx.x >> 3) & (NC-1);
  const int b = blockIdx.x >> 8;
  const int c = cblk*256 + tid;
  const int tlo = dir ? (TTL - (k+1)*CL) : k*CL;
  {
    const float4* src = (const float4*)(bcpk + ((long)b*TTL + tlo)*32);
    float4* dst = (float4*)bc;
    #pragma unroll
    for (int i=0;i<(CL*8)/256;i++) dst[tid + i*256] = src[tid + i*256];
  }
  __syncthreads();

  float Aa[16];
  #pragma unroll
  for (int qg=0;qg<4;qg++){
    float4 t4 = *(const float4*)(A_log + (long)c*DSN + qg*4);
    Aa[qg*4+0] = -__expf(t4.x); Aa[qg*4+1] = -__expf(t4.y);
    Aa[qg*4+2] = -__expf(t4.z); Aa[qg*4+3] = -__expf(t4.w);
  }
  const float Dpc = Dp[c];
  float h[16];
  {
    long o = ((long)(b*NC + k)*DSN)*DI + c;
    #pragma unroll
    for (int s=0;s<16;s++) h[s] = hpart[o + (long)s*DI];
  }

  const int tstart = dir ? (TTL-1 - k*CL) : k*CL;
  const long step = dir ? -(long)DI : (long)DI;
  const float* dtp = dt + ((long)b*TTL + tstart)*DI + c;
  const hbf*   xcp = xc + ((long)b*TTL + tstart)*DI + c;
  const hbf*   zp  = z  + ((long)b*TTL + tstart)*DI + c;
  hbf*         yp  = y  + ((long)b*TTL + tstart)*DI + c;
  float dtv = *dtp, xv = b2f(*xcp); hbf zv = *zp;

  #pragma unroll 1
  for (int i=0;i<CL;i++){
    float dtn = dtv, xn = xv; hbf zn = zv;
    if (i+1 < CL){ dtp += step; xcp += step; zp += step; dtn = *dtp; xn = b2f(*xcp); zn = *zp; }
    const int r = dir ? (CL-1-i) : i;
    const float* bcr = bc + r*32;
    const float t1 = dtv*xv;
    float ps = 0.f;
    #pragma unroll
    for (int sg=0;sg<4;sg++){
      float4 Bv = *(const float4*)(bcr + sg*4);
      float4 Cv = *(const float4*)(bcr + 16 + sg*4);
      float a0 = __expf(dtv*Aa[sg*4+0]); h[sg*4+0]=a0*h[sg*4+0]+t1*Bv.x; ps += h[sg*4+0]*Cv.x;
      float a1 = __expf(dtv*Aa[sg*4+1]); h[sg*4+1]=a1*h[sg*4+1]+t1*Bv.y; ps += h[sg*4+1]*Cv.y;
      float a2 = __expf(dtv*Aa[sg*4+2]); h[sg*4+2]=a2*h[sg*4+2]+t1*Bv.z; ps += h[sg*4+2]*Cv.z;
      float a3 = __expf(dtv*Aa[sg*4+3]); h[sg*4+3]=a3*h[sg*4+3]+t1*Bv.w; ps += h[sg*4+3]*Cv.w;
    }
    float zf = b2f(zv);
    *yp = f2b((ps + xv*Dpc) * (zf * sigmoid_f(zf)));
    yp += step;
    dtv = dtn; xv = xn; zv = zn;
  }
}

extern "C" void kernel_launch(void* const* d_in, const int* in_sizes, int n_in,
                              void* d_out, int out_size, void* d_ws, size_t ws_size,
                              hipStream_t stream) {
  const float* x       = (const float*)d_in[0];
  const float* u       = (const float*)d_in[1];
  const float* alphap  = (const float*)d_in[2];
  const float* W_delta = (const float*)d_in[3];
  const float* b_delta = (const float*)d_in[4];
  const float* W_proj  = (const float*)d_in[5];
  const float* b_proj  = (const float*)d_in[6];

  // workspace layout (byte offsets), total 146,538,496 B = 146.5 MB
  char* W = (char*)d_ws;
  float* dtb    = (float*)(W + 0);            // 4096*2048 f32
  float* bcpk   = (float*)(W + 33554432);     // 4096*32 f32
  float* hpart  = (float*)(W + 34078720);     // 2*32*16*2048 f32
  float* Ppart  = (float*)(W + 42467328);     // same
  hbf* zbf      = (hbf*)(W + 50855936);       // 4096*2048 bf16
  hbf* xi_y_bf  = (hbf*)(W + 67633152);       // 4096*2048 bf16 (xi then y)
  hbf* xc_bf    = (hbf*)(W + 84410368);       // 4096*2048 bf16
  hbf* xg_bf    = (hbf*)(W + 101187584);      // 4096*1024 bf16
  hbf* cat_bf   = (hbf*)(W + 109576192);      // 4096*2048 bf16
  hbf* xw_bf    = (hbf*)(W + 126353408);      // 4M bf16 (x_bf, then Wt_in per dir)
  hbf* Wt_delta = (hbf*)(W + 134742016);      // 1024*1024
  hbf* Wt_proj  = (hbf*)(W + 136839168);      // 1024*2048
  hbf* Wt_out   = (hbf*)(W + 141033472);      // 1024*2048
  hbf* Wt_x     = (hbf*)(W + 145227776);      // 128*2048 (pad from 96)
  hbf* Wt_dt    = (hbf*)(W + 145752064);      // 2048*64
  hbf* dtlo_bf  = (hbf*)(W + 146014208);      // 4096*64

  float* o_main = (float*)d_out;
  float* o_fwd  = o_main + 4194304;
  float* o_bwd  = o_main + 2*4194304;

  // upfront converts
  cvt_bf<<<MM*DM/1024, 256, 0, stream>>>(x, xw_bf);
  trans_bf<<<dim3(DM/32, DM/32), 256, 0, stream>>>(W_delta, Wt_delta, DM, DM);
  trans_bf<<<dim3(2*DM/32, DM/32), 256, 0, stream>>>(W_proj, Wt_proj, 2*DM, DM);

  // G1: x @ W_delta + gate epilogue -> x_gated (bf16)
  {
    MGemmP p{};
    p.A = xw_bf; p.lda = DM; p.Bt = Wt_delta; p.ldb = DM; p.N = DM; p.K = DM;
    p.bias = b_delta; p.ob0 = xg_bf; p.ldob0 = DM;
    p.x = x; p.u = u; p.alpha = alphap;
    mgemm_k<0><<<dim3(MM/128, DM/128), 256, 0, stream>>>(p);
  }

  for (int dir = 0; dir < 2; dir++){
    const int base = 7 + 9*dir;
    const float* W_in   = (const float*)d_in[base+0];
    const float* conv_w = (const float*)d_in[base+1];
    const float* conv_b = (const float*)d_in[base+2];
    const float* W_x    = (const float*)d_in[base+3];
    const float* W_dt   = (const float*)d_in[base+4];
    const float* b_dt   = (const float*)d_in[base+5];
    const float* A_log  = (const float*)d_in[base+6];
    const float* Dp     = (const float*)d_in[base+7];
    const float* W_out  = (const float*)d_in[base+8];

    // per-dir weight transposes (xw_bf region free after G1 / prior dir)
    trans_bf<<<dim3(DM/32, 4096/32), 256, 0, stream>>>(W_in, xw_bf, DM, 2*DI);
    trans_bf<<<dim3(DI/32, 128/32), 256, 0, stream>>>(W_x, Wt_x, DI, 96);
    trans_bf<<<dim3(DTR/32, DI/32), 256, 0, stream>>>(W_dt, Wt_dt, DTR, DI);
    trans_bf<<<dim3(DI/32, DM/32), 256, 0, stream>>>(W_out, Wt_out, DI, DM);

    // G2: xz = x_gated @ W_in -> xi (bf16) | z (bf16)
    {
      MGemmP p{};
      p.A = xg_bf; p.lda = DM; p.Bt = xw_bf; p.ldb = DM; p.N = 2*DI; p.K = DM;
      p.ob0 = xi_y_bf; p.ob1 = zbf;
      mgemm_k<1><<<dim3(MM/128, (2*DI)/128), 256, 0, stream>>>(p);
    }
    conv_silu_k<<<(MM*DI)/256, 256, 0, stream>>>(xi_y_bf, conv_w, conv_b, xc_bf, dir);
    // G3: xdb = xc @ W_x (N=96, padded B) -> dtlo bf16 + packed B/C f32
    {
      MGemmP p{};
      p.A = xc_bf; p.lda = DI; p.Bt = Wt_x; p.ldb = DI; p.N = 96; p.K = DI;
      p.out0 = bcpk; p.ob0 = dtlo_bf;
      mgemm_k<2><<<dim3(MM/128, 1), 256, 0, stream>>>(p);
    }
    // G4: dt = softplus(dt_lo @ W_dt + b_dt) -> f32
    {
      MGemmP p{};
      p.A = dtlo_bf; p.lda = DTR; p.Bt = Wt_dt; p.ldb = DTR; p.N = DI; p.K = DTR;
      p.bias = b_dt; p.out0 = dtb; p.ldo0 = DI;
      mgemm_k<3><<<dim3(MM/128, DI/128), 256, 0, stream>>>(p);
    }
    // scan
    scan_p1<<<BB*NC*(DI/256), 256, 0, stream>>>(dtb, bcpk, xc_bf, A_log, hpart, Ppart, dir);
    scan_p2<<<(BB*DI*DSN)/256, 256, 0, stream>>>(hpart, Ppart);
    scan_p3<<<BB*NC*(DI/256), 256, 0, stream>>>(dtb, bcpk, xc_bf, zbf, A_log, Dp, hpart, xi_y_bf, dir);
    // G7: dir_out = y @ W_out -> fp32 output + bf16 cat
    {
      MGemmP p{};
      p.A = xi_y_bf; p.lda = DI; p.Bt = Wt_out; p.ldb = DI; p.N = DM; p.K = DI;
      p.out0 = dir ? o_bwd : o_fwd; p.ldo0 = DM;
      p.ob0 = cat_bf; p.ldob0 = 2*DM; p.col0 = dir*DM;
      mgemm_k<4><<<dim3(MM/128, DM/128), 256, 0, stream>>>(p);
    }
  }

  // G8: out = cat @ W_proj + b_proj -> fp32
  {
    MGemmP p{};
    p.A = cat_bf; p.lda = 2*DM; p.Bt = Wt_proj; p.ldb = 2*DM; p.N = DM; p.K = 2*DM;
    p.bias = b_proj; p.out0 = o_main; p.ldo0 = DM;
    mgemm_k<5><<<dim3(MM/128, DM/128), 256, 0, stream>>>(p);
  }
}